// Round 10
// baseline (367.896 us; speedup 1.0000x reference)
//
#include <hip/hip_runtime.h>

#define NPTS 8192
#define KSEL 33    // rank 0 (self) + 32 neighbors
#define SCAP 512   // survivor capacity (threshold lands ~global rank 100-150)
#define PPB  8     // points per persistent block
#define NBLK (NPTS / PPB)   // 1024 blocks -> 4/CU, whole grid co-resident

typedef float vf4 __attribute__((ext_vector_type(4)));

// Block-wide sync that is LDS-coherent but does NOT drain vmcnt:
// s_waitcnt lgkmcnt(0) + raw s_barrier. __syncthreads() would emit
// s_waitcnt vmcnt(0) and stall on the previous point's NT gather stores;
// this keeps them draining in the background across iterations.
__device__ __forceinline__ void sync_lds() {
    asm volatile("s_waitcnt lgkmcnt(0)" ::: "memory");
    __builtin_amdgcn_s_barrier();
}

// ---------------------------------------------------------------------------
// Prep: pts4[j] = (x, y, z, sq), sq = (x*x + y*y) + z*z in exact reference
// rounding order (contract off, separate mul/add).
// ---------------------------------------------------------------------------
__global__ __launch_bounds__(256) void prep_kernel(const float* __restrict__ pts,
                                                   float4* __restrict__ pts4) {
#pragma clang fp contract(off)
    const int j = blockIdx.x * 256 + threadIdx.x;
    const float x = pts[j * 3 + 0];
    const float y = pts[j * 3 + 1];
    const float z = pts[j * 3 + 2];
    const float sq = (x * x + y * y) + z * z;
    pts4[j] = make_float4(x, y, z, sq);
}

// ---------------------------------------------------------------------------
// Persistent fused exact-kNN + gather. Each block loops over 8 points; the
// per-point pipeline is byte-identical math to the round-9 passing kernel
// (bit-identical thresholds / survivors / ranks / output). The win is
// structural: gather(p)'s NT stores overlap select(p+1)'s VALU because the
// inter-phase barriers never wait on vmcnt.
//
// LDS WAR audit across iterations: red / S / jlist / sh_cnt each have >= 1
// barrier between last-read(p) and first-write(p+1) on all wave paths.
// ---------------------------------------------------------------------------
__global__ __launch_bounds__(256) void knn_fused_kernel(const float4* __restrict__ pts4,
                                                        const float* __restrict__ feats,
                                                        float* __restrict__ out) {
#pragma clang fp contract(off)
    const int tid = threadIdx.x;
    const int lane = tid & 63;
    const int wv = tid >> 6;

    __shared__ unsigned red[4];
    __shared__ int sh_cnt;
    __shared__ unsigned long long S[SCAP];
    __shared__ unsigned jlist[32];

    const unsigned long long O1 = (unsigned long long)NPTS * 256ull;
    const unsigned long long O2 = O1 + (unsigned long long)NPTS * 2048ull;
    const unsigned long long O3 = O2 + (unsigned long long)NPTS * 4096ull;

    for (int it = 0; it < PPB; ++it) {
        const int i = blockIdx.x * PPB + it;
        const float4 pi = pts4[i];

        // --- dist loop: exact reference d2 bits, 2-min tracking ---
        unsigned d[32];
        unsigned m1 = 0xFFFFFFFFu, m2 = 0xFFFFFFFFu;
#pragma unroll
        for (int t = 0; t < 32; ++t) {
            const int j = tid + t * 256;
            const float4 pj = pts4[j];
            const float dot = __builtin_fmaf(pi.z, pj.z,
                               __builtin_fmaf(pi.y, pj.y, pi.x * pj.x));
            const float d2 = (pi.w + pj.w) - (2.0f * dot);
            const unsigned db = __float_as_uint(fmaxf(d2, 0.0f));
            d[t] = db;
            const unsigned mx = db > m1 ? db : m1;
            m1 = db < m1 ? db : m1;
            m2 = mx < m2 ? mx : m2;
        }
        if (tid == 0) sh_cnt = 0;   // prev iter's readers are past B3(p-1)

        // --- per-wave ballot binary search: 33rd smallest of {m1,m2} ---
        unsigned blo = 0u, bhi = 0x7F800000u;
        while (blo < bhi) {
            const unsigned mid = (blo + bhi) >> 1;
            const int cnt = __popcll(__ballot(m1 <= mid)) +
                            __popcll(__ballot(m2 <= mid));
            if (cnt >= KSEL) bhi = mid; else blo = mid + 1u;
        }
        if (lane == 0) red[wv] = bhi;
        sync_lds();                                   // B1
        unsigned T = red[0];
        T = red[1] < T ? red[1] : T;
        T = red[2] < T ? red[2] : T;
        T = red[3] < T ? red[3] : T;

        // --- widen to sqrt-closure (conservative, provably inclusive) ---
        const float s = sqrtf(__uint_as_float(T));            // CR sqrt
        const float snx = __uint_as_float(__float_as_uint(s) + 1u);
        const unsigned T2 = __float_as_uint(__fmul_rn(snx, snx)) + 2u;

        // --- compact survivors into LDS (CR sqrt only for survivors) ---
        int n = 0;
#pragma unroll
        for (int t = 0; t < 32; ++t) n += (d[t] <= T2) ? 1 : 0;

        int incl = n;
#pragma unroll
        for (int sh = 1; sh < 64; sh <<= 1) {
            const int o = __shfl_up(incl, sh, 64);
            if (lane >= sh) incl += o;
        }
        int base = 0;
        if (lane == 63) base = atomicAdd(&sh_cnt, incl);
        base = __shfl(base, 63, 64);
        int ptr = base + incl - n;
#pragma unroll
        for (int t = 0; t < 32; ++t) {
            if (d[t] <= T2) {
                const unsigned db = __float_as_uint(sqrtf(__uint_as_float(d[t])));
                if (ptr < SCAP)
                    S[ptr] = (((unsigned long long)db) << 32) | (unsigned)(tid + t * 256);
                ++ptr;
            }
        }
        sync_lds();                                   // B2

        // --- exact global rank among survivors (keys unique via j) ---
        const int c = sh_cnt < SCAP ? sh_cnt : SCAP;
        for (int q = tid; q < c; q += 256) {
            const unsigned long long key = S[q];
            int rank = 0;
            for (int u = 0; u < c; ++u) rank += (S[u] < key) ? 1 : 0;
            if (rank >= 1 && rank < KSEL) jlist[rank - 1] = (unsigned)key;
        }
        sync_lds();                                   // B3

        // --- gather: read-once / store-many, NT stores left in flight ---
        const unsigned long long ii = (unsigned long long)i;

        vf4 vself;
        if (wv == 0) {
            const vf4* sp = (const vf4*)(feats + ii * 256ull);
            vself = sp[lane];
        }
        vf4 vk[8];
#pragma unroll
        for (int m = 0; m < 8; ++m) {
            const unsigned src = jlist[wv + 4 * m];
            const vf4* sp = (const vf4*)(feats + (unsigned long long)src * 256ull);
            vk[m] = sp[lane];
        }

        if (wv == 0) {
            __builtin_nontemporal_store(vself, &((vf4*)(out + ii * 256ull))[lane]);
        }
#pragma unroll
        for (int m = 0; m < 8; ++m) {
            const unsigned k = (unsigned)(wv + 4 * m);
            const vf4 v = vk[m];
            __builtin_nontemporal_store(v,
                &((vf4*)(out + O3 + ii * 8192ull + (unsigned long long)k * 256ull))[lane]);
            if (k < 16u)
                __builtin_nontemporal_store(v,
                    &((vf4*)(out + O2 + ii * 4096ull + (unsigned long long)k * 256ull))[lane]);
            if (k < 8u)
                __builtin_nontemporal_store(v,
                    &((vf4*)(out + O1 + ii * 2048ull + (unsigned long long)k * 256ull))[lane]);
        }
        // no barrier here: next iteration's dist loop overlaps store drain
    }
}

extern "C" void kernel_launch(void* const* d_in, const int* in_sizes, int n_in,
                              void* d_out, int out_size, void* d_ws, size_t ws_size,
                              hipStream_t stream) {
    const float* feats = (const float*)d_in[0];   // (8192, 256) f32
    const float* pts = (const float*)d_in[1];     // (8192, 3)   f32
    // d_in[2] = f_masks (all ones; unused by the reference computation)

    float4* pts4 = (float4*)d_ws;                 // 128 KB scratch

    prep_kernel<<<NPTS / 256, 256, 0, stream>>>(pts, pts4);
    knn_fused_kernel<<<NBLK, 256, 0, stream>>>(pts4, feats, (float*)d_out);
}

// Round 11
// 176.816 us; speedup vs baseline: 2.0807x; 2.0807x over previous
//
#include <hip/hip_runtime.h>

#define NPTS 8192
#define KSEL 33    // rank 0 (self) + 32 neighbors
#define SCAP 512   // survivor capacity (per-wave 33rd-of-2048-sample threshold
                   // lands at global rank ~100-150; 128 was too small (round 7))

typedef float vf4 __attribute__((ext_vector_type(4)));

// ---------------------------------------------------------------------------
// Prep: pts4[j] = (x, y, z, sq), sq = (x*x + y*y) + z*z in exact reference
// rounding order (contract off, separate mul/add).
// ---------------------------------------------------------------------------
__global__ __launch_bounds__(256) void prep_kernel(const float* __restrict__ pts,
                                                   float4* __restrict__ pts4) {
#pragma clang fp contract(off)
    const int j = blockIdx.x * 256 + threadIdx.x;
    const float x = pts[j * 3 + 0];
    const float y = pts[j * 3 + 1];
    const float z = pts[j * 3 + 2];
    const float sq = (x * x + y * y) + z * z;
    pts4[j] = make_float4(x, y, z, sq);
}

// ---------------------------------------------------------------------------
// Fused exact-kNN + gather. One block (256 threads) per point i — the
// round-9 structure (block-per-point; cross-block turnover overlaps one
// block's NT-store drain with other blocks' select VALU; round 10 proved
// in-wave persistent loops stall dist loads behind the shared vmcnt FIFO).
//
// __launch_bounds__(256, 4): cap VGPRs at 128. Measured VGPR_Count was 132 —
// 4 registers over the 128-VGPR occupancy cliff (8 -> 16 waves/CU).
//
// Selection math byte-identical to rounds 6/9 (bit-identical output):
//   d2 filter via per-thread 2-min + per-wave ballot binary search ->
//   sqrt-closure widen -> compact survivors (CR sqrt only there) ->
//   all-pairs rank on (dist<<32|j) = lax.top_k order.
// Gather: read-once / store-many (out1/out2 rows are prefixes of out3's),
// 8 up-front row loads per wave, NT float4 stores.
// ---------------------------------------------------------------------------
__global__ __launch_bounds__(256, 4) void knn_fused_kernel(const float4* __restrict__ pts4,
                                                           const float* __restrict__ feats,
                                                           float* __restrict__ out) {
#pragma clang fp contract(off)
    const int i = blockIdx.x;
    const int tid = threadIdx.x;
    const int lane = tid & 63;
    const int wv = tid >> 6;

    __shared__ unsigned red[4];
    __shared__ int sh_cnt;
    __shared__ unsigned long long S[SCAP];
    __shared__ unsigned jlist[32];

    const float4 pi = pts4[i];

    unsigned d[32];                       // clamped-d2 bits per owned j
    unsigned m1 = 0xFFFFFFFFu, m2 = 0xFFFFFFFFu;
#pragma unroll
    for (int t = 0; t < 32; ++t) {
        const int j = tid + t * 256;
        const float4 pj = pts4[j];
        const float dot = __builtin_fmaf(pi.z, pj.z, __builtin_fmaf(pi.y, pj.y, pi.x * pj.x));
        const float d2 = (pi.w + pj.w) - (2.0f * dot);
        const unsigned db = __float_as_uint(fmaxf(d2, 0.0f));
        d[t] = db;
        const unsigned mx = db > m1 ? db : m1;   // max(db, m1)
        m1 = db < m1 ? db : m1;                  // min
        m2 = mx < m2 ? mx : m2;                  // 2nd smallest
    }
    if (tid == 0) sh_cnt = 0;

    // --- per-wave ballot binary search: exact 33rd smallest of {m1,m2} ---
    unsigned blo = 0u, bhi = 0x7F800000u;        // finite non-neg float bits
    while (blo < bhi) {
        const unsigned mid = (blo + bhi) >> 1;
        const int cnt = __popcll(__ballot(m1 <= mid)) + __popcll(__ballot(m2 <= mid));
        if (cnt >= KSEL) bhi = mid; else blo = mid + 1u;
    }
    if (lane == 0) red[wv] = bhi;
    __syncthreads();
    unsigned T = red[0];
    T = red[1] < T ? red[1] : T;
    T = red[2] < T ? red[2] : T;
    T = red[3] < T ? red[3] : T;

    // --- widen to sqrt-closure (conservative, provably inclusive) ---
    const float s = sqrtf(__uint_as_float(T));               // CR sqrt
    const float snx = __uint_as_float(__float_as_uint(s) + 1u);
    const unsigned T2 = __float_as_uint(__fmul_rn(snx, snx)) + 2u;

    // --- compact survivors into LDS (CR sqrt only here) ---
    int n = 0;
#pragma unroll
    for (int t = 0; t < 32; ++t) n += (d[t] <= T2) ? 1 : 0;

    int incl = n;
#pragma unroll
    for (int sh = 1; sh < 64; sh <<= 1) {
        const int o = __shfl_up(incl, sh, 64);
        if (lane >= sh) incl += o;
    }
    int base = 0;
    if (lane == 63) base = atomicAdd(&sh_cnt, incl);
    base = __shfl(base, 63, 64);
    int ptr = base + incl - n;
#pragma unroll
    for (int t = 0; t < 32; ++t) {
        if (d[t] <= T2) {
            const unsigned db = __float_as_uint(sqrtf(__uint_as_float(d[t])));
            if (ptr < SCAP)
                S[ptr] = (((unsigned long long)db) << 32) | (unsigned)(tid + t * 256);
            ++ptr;
        }
    }
    __syncthreads();

    // --- exact global rank among survivors (keys unique via j) ---
    const int c = sh_cnt < SCAP ? sh_cnt : SCAP;
    for (int q = tid; q < c; q += 256) {
        const unsigned long long key = S[q];
        int rank = 0;
        for (int u = 0; u < c; ++u) rank += (S[u] < key) ? 1 : 0;
        if (rank >= 1 && rank < KSEL) jlist[rank - 1] = (unsigned)key;
    }
    __syncthreads();

    // --- gather: read-once / store-many ---
    const unsigned long long O1 = (unsigned long long)NPTS * 256ull;
    const unsigned long long O2 = O1 + (unsigned long long)NPTS * 2048ull;
    const unsigned long long O3 = O2 + (unsigned long long)NPTS * 4096ull;
    const unsigned long long ii = (unsigned long long)i;

    // issue all row-reads first (8 neighbor rows per wave, + self on wave 0)
    vf4 vself;
    if (wv == 0) {
        const vf4* sp = (const vf4*)(feats + ii * 256ull);
        vself = sp[lane];
    }
    vf4 vk[8];
    unsigned kk[8];
#pragma unroll
    for (int m = 0; m < 8; ++m) {
        const int k = wv + 4 * m;
        const unsigned src = jlist[k];
        kk[m] = (unsigned)k;
        const vf4* sp = (const vf4*)(feats + (unsigned long long)src * 256ull);
        vk[m] = sp[lane];
    }

    // stores: out3 always; mirror to out2 (k<16) and out1 (k<8)
    if (wv == 0) {
        __builtin_nontemporal_store(vself, &((vf4*)(out + ii * 256ull))[lane]);
    }
#pragma unroll
    for (int m = 0; m < 8; ++m) {
        const unsigned k = kk[m];
        const vf4 v = vk[m];
        __builtin_nontemporal_store(v,
            &((vf4*)(out + O3 + ii * 8192ull + (unsigned long long)k * 256ull))[lane]);
        if (k < 16u)
            __builtin_nontemporal_store(v,
                &((vf4*)(out + O2 + ii * 4096ull + (unsigned long long)k * 256ull))[lane]);
        if (k < 8u)
            __builtin_nontemporal_store(v,
                &((vf4*)(out + O1 + ii * 2048ull + (unsigned long long)k * 256ull))[lane]);
    }
}

extern "C" void kernel_launch(void* const* d_in, const int* in_sizes, int n_in,
                              void* d_out, int out_size, void* d_ws, size_t ws_size,
                              hipStream_t stream) {
    const float* feats = (const float*)d_in[0];   // (8192, 256) f32
    const float* pts = (const float*)d_in[1];     // (8192, 3)   f32
    // d_in[2] = f_masks (all ones; unused by the reference computation)

    float4* pts4 = (float4*)d_ws;                 // 128 KB scratch

    prep_kernel<<<NPTS / 256, 256, 0, stream>>>(pts, pts4);
    knn_fused_kernel<<<NPTS, 256, 0, stream>>>(pts4, feats, (float*)d_out);
}

// Round 12
// 149.537 us; speedup vs baseline: 2.4602x; 1.1824x over previous
//
#include <hip/hip_runtime.h>

#define NPTS 8192
#define KSEL 33    // rank 0 (self) + 32 neighbors
#define SCAP 512   // survivor capacity (per-wave 33rd-of-2048-sample threshold
                   // lands at global rank ~100-150; 128 was too small (round 7))

typedef float vf4 __attribute__((ext_vector_type(4)));

// ---------------------------------------------------------------------------
// Prep: pts4[j] = (x, y, z, sq), sq = (x*x + y*y) + z*z in exact reference
// rounding order (contract off, separate mul/add).
// ---------------------------------------------------------------------------
__global__ __launch_bounds__(256) void prep_kernel(const float* __restrict__ pts,
                                                   float4* __restrict__ pts4) {
#pragma clang fp contract(off)
    const int j = blockIdx.x * 256 + threadIdx.x;
    const float x = pts[j * 3 + 0];
    const float y = pts[j * 3 + 1];
    const float z = pts[j * 3 + 2];
    const float sq = (x * x + y * y) + z * z;
    pts4[j] = make_float4(x, y, z, sq);
}

// ---------------------------------------------------------------------------
// Fused exact-kNN + gather. One block (256 threads) per point i (round-9
// structure; round 10 proved persistent in-wave loops stall dist loads
// behind the shared vmcnt FIFO, round 11 proved launch_bounds-forced 128
// VGPR spills). This round: sched_barrier(0) every 8 dist iterations caps
// the scheduler at 8 in-flight pts4 loads (32 VGPR of pipelining instead of
// ~128) WITHOUT partial unroll (d[t] indices stay compile-time, no scratch).
// Goal: VGPR ~132 -> <=100, 3 -> 5 blocks/CU, better select/gather overlap
// across blocks.
//
// Selection math byte-identical to rounds 6/9 (bit-identical output):
//   d2 filter via per-thread 2-min + per-wave ballot binary search ->
//   sqrt-closure widen -> compact survivors (CR sqrt only there) ->
//   all-pairs rank on (dist<<32|j) = lax.top_k order.
// Gather: read-once / store-many (out1/out2 rows are prefixes of out3's),
// 8 up-front row loads per wave, NT float4 stores.
// ---------------------------------------------------------------------------
__global__ __launch_bounds__(256) void knn_fused_kernel(const float4* __restrict__ pts4,
                                                        const float* __restrict__ feats,
                                                        float* __restrict__ out) {
#pragma clang fp contract(off)
    const int i = blockIdx.x;
    const int tid = threadIdx.x;
    const int lane = tid & 63;
    const int wv = tid >> 6;

    __shared__ unsigned red[4];
    __shared__ int sh_cnt;
    __shared__ unsigned long long S[SCAP];
    __shared__ unsigned jlist[32];

    const float4 pi = pts4[i];

    unsigned d[32];                       // clamped-d2 bits per owned j
    unsigned m1 = 0xFFFFFFFFu, m2 = 0xFFFFFFFFu;
#pragma unroll
    for (int t = 0; t < 32; ++t) {
        const int j = tid + t * 256;
        const float4 pj = pts4[j];
        const float dot = __builtin_fmaf(pi.z, pj.z, __builtin_fmaf(pi.y, pj.y, pi.x * pj.x));
        const float d2 = (pi.w + pj.w) - (2.0f * dot);
        const unsigned db = __float_as_uint(fmaxf(d2, 0.0f));
        d[t] = db;
        const unsigned mx = db > m1 ? db : m1;   // max(db, m1)
        m1 = db < m1 ? db : m1;                  // min
        m2 = mx < m2 ? mx : m2;                  // 2nd smallest
        // scheduling fence every 8 iters: limits in-flight loads (VGPR cap)
        if ((t & 7) == 7) __builtin_amdgcn_sched_barrier(0);
    }
    if (tid == 0) sh_cnt = 0;

    // --- per-wave ballot binary search: exact 33rd smallest of {m1,m2} ---
    unsigned blo = 0u, bhi = 0x7F800000u;        // finite non-neg float bits
    while (blo < bhi) {
        const unsigned mid = (blo + bhi) >> 1;
        const int cnt = __popcll(__ballot(m1 <= mid)) + __popcll(__ballot(m2 <= mid));
        if (cnt >= KSEL) bhi = mid; else blo = mid + 1u;
    }
    if (lane == 0) red[wv] = bhi;
    __syncthreads();
    unsigned T = red[0];
    T = red[1] < T ? red[1] : T;
    T = red[2] < T ? red[2] : T;
    T = red[3] < T ? red[3] : T;

    // --- widen to sqrt-closure (conservative, provably inclusive) ---
    const float s = sqrtf(__uint_as_float(T));               // CR sqrt
    const float snx = __uint_as_float(__float_as_uint(s) + 1u);
    const unsigned T2 = __float_as_uint(__fmul_rn(snx, snx)) + 2u;

    // --- compact survivors into LDS (CR sqrt only here) ---
    int n = 0;
#pragma unroll
    for (int t = 0; t < 32; ++t) n += (d[t] <= T2) ? 1 : 0;

    int incl = n;
#pragma unroll
    for (int sh = 1; sh < 64; sh <<= 1) {
        const int o = __shfl_up(incl, sh, 64);
        if (lane >= sh) incl += o;
    }
    int base = 0;
    if (lane == 63) base = atomicAdd(&sh_cnt, incl);
    base = __shfl(base, 63, 64);
    int ptr = base + incl - n;
#pragma unroll
    for (int t = 0; t < 32; ++t) {
        if (d[t] <= T2) {
            const unsigned db = __float_as_uint(sqrtf(__uint_as_float(d[t])));
            if (ptr < SCAP)
                S[ptr] = (((unsigned long long)db) << 32) | (unsigned)(tid + t * 256);
            ++ptr;
        }
    }
    __syncthreads();

    // --- exact global rank among survivors (keys unique via j) ---
    const int c = sh_cnt < SCAP ? sh_cnt : SCAP;
    for (int q = tid; q < c; q += 256) {
        const unsigned long long key = S[q];
        int rank = 0;
        for (int u = 0; u < c; ++u) rank += (S[u] < key) ? 1 : 0;
        if (rank >= 1 && rank < KSEL) jlist[rank - 1] = (unsigned)key;
    }
    __syncthreads();

    // --- gather: read-once / store-many ---
    const unsigned long long O1 = (unsigned long long)NPTS * 256ull;
    const unsigned long long O2 = O1 + (unsigned long long)NPTS * 2048ull;
    const unsigned long long O3 = O2 + (unsigned long long)NPTS * 4096ull;
    const unsigned long long ii = (unsigned long long)i;

    // issue all row-reads first (8 neighbor rows per wave, + self on wave 0)
    vf4 vself;
    if (wv == 0) {
        const vf4* sp = (const vf4*)(feats + ii * 256ull);
        vself = sp[lane];
    }
    vf4 vk[8];
    unsigned kk[8];
#pragma unroll
    for (int m = 0; m < 8; ++m) {
        const int k = wv + 4 * m;
        const unsigned src = jlist[k];
        kk[m] = (unsigned)k;
        const vf4* sp = (const vf4*)(feats + (unsigned long long)src * 256ull);
        vk[m] = sp[lane];
    }

    // stores: out3 always; mirror to out2 (k<16) and out1 (k<8)
    if (wv == 0) {
        __builtin_nontemporal_store(vself, &((vf4*)(out + ii * 256ull))[lane]);
    }
#pragma unroll
    for (int m = 0; m < 8; ++m) {
        const unsigned k = kk[m];
        const vf4 v = vk[m];
        __builtin_nontemporal_store(v,
            &((vf4*)(out + O3 + ii * 8192ull + (unsigned long long)k * 256ull))[lane]);
        if (k < 16u)
            __builtin_nontemporal_store(v,
                &((vf4*)(out + O2 + ii * 4096ull + (unsigned long long)k * 256ull))[lane]);
        if (k < 8u)
            __builtin_nontemporal_store(v,
                &((vf4*)(out + O1 + ii * 2048ull + (unsigned long long)k * 256ull))[lane]);
    }
}

extern "C" void kernel_launch(void* const* d_in, const int* in_sizes, int n_in,
                              void* d_out, int out_size, void* d_ws, size_t ws_size,
                              hipStream_t stream) {
    const float* feats = (const float*)d_in[0];   // (8192, 256) f32
    const float* pts = (const float*)d_in[1];     // (8192, 3)   f32
    // d_in[2] = f_masks (all ones; unused by the reference computation)

    float4* pts4 = (float4*)d_ws;                 // 128 KB scratch

    prep_kernel<<<NPTS / 256, 256, 0, stream>>>(pts, pts4);
    knn_fused_kernel<<<NPTS, 256, 0, stream>>>(pts4, feats, (float*)d_out);
}